// Round 18
// baseline (827.694 us; speedup 1.0000x reference)
//
#include <hip/hip_runtime.h>
#include <hip/hip_bf16.h>

typedef unsigned short u16;
typedef unsigned char u8;
typedef float f32x4 __attribute__((ext_vector_type(4)));
typedef int i32x4v __attribute__((ext_vector_type(4)));
typedef int i32x8v __attribute__((ext_vector_type(8)));

#define N_ 4096
#define D_ 3072

// ---------------- static device workspace ----------------
__device__ __align__(256) u8   g_Feat8[(size_t)2 * N_ * D_];     // fp8 [G rows ; P rows]
__device__ __align__(256) u8   g_BT[(size_t)(D_ + 64) * 2 * N_]; // fp8 [3072(+64)][8192] = [PbT | GbT]
__device__ __align__(256) u8   g_Wall[(size_t)3 * N_ * 2 * N_];  // fp8 [tau][4096][8192] = [Wp | -Wn]
__device__ __align__(256) float g_Sp[(size_t)N_ * N_];           // dist_pos
__device__ __align__(256) float g_Sn[(size_t)N_ * N_];           // dist_neg (+diag mask)
__device__ __align__(256) float g_Vall[(size_t)2 * N_ * D_];     // V_0, V_1 only (V_2 never stored)
__device__ float g_ng[N_], g_np[N_];
__device__ float g_rminp[N_], g_rminn[N_], g_cminp[N_];          // via atomicMin in S-GEMM
__device__ float g_R [3 * N_];    // rsqrt(row exp-sums)
__device__ float g_Cp[3 * N_];    // rsqrt(col exp-sums, pos)
__device__ float g_Cn[3 * N_];    // rsqrt(col exp-sums, neg = row sums by symmetry)
__device__ float g_Cpart[8 * 3 * N_];
__device__ float g_part6[6 * 512];   // Gram partials G00,G11,G22,G01,G02,G12

// ---------------- helpers ----------------
__device__ __forceinline__ u16 cvt2fp8(float a, float b) {
    return (u16)(__builtin_amdgcn_cvt_pk_fp8_f32(a, b, 0, false) & 0xffff);
}
__device__ __forceinline__ u8 cvt1fp8(float a) {
    return (u8)(__builtin_amdgcn_cvt_pk_fp8_f32(a, a, 0, false) & 0xff);
}

// exp chain: from e1 = exp(5x) derive e20 = e1^4, e50 = e1^10 (4 muls)
#define EXPCHAIN(x5, E5, E20, E50) \
    float E5 = __expf(x5); float E5##_2 = E5 * E5; float E20 = E5##_2 * E5##_2; \
    float E50 = E20 * E20 * E5##_2;

__device__ __forceinline__ float blockSum256(float v) {
    __shared__ float red[4];
#pragma unroll
    for (int s = 32; s; s >>= 1) v += __shfl_down(v, s, 64);
    int l = threadIdx.x & 63, w = threadIdx.x >> 6;
    if (l == 0) red[w] = v;
    __syncthreads();
    float r = red[0] + red[1] + red[2] + red[3];
    __syncthreads();
    return r;
}

__device__ __forceinline__ void gload16(const void* g, void* lds) {
    __builtin_amdgcn_global_load_lds(
        (const __attribute__((address_space(1))) void*)g,
        (__attribute__((address_space(3))) void*)lds, 16, 0, 0);
}

__device__ __forceinline__ void atomicMinF(float* p, float v) {
    atomicMin((unsigned int*)p, __float_as_uint(v));   // exact for v >= 0
}

// ---------------- fused convert(fp8) + row norms + transpose (128-col strips) -
__global__ __launch_bounds__(256) void k_convtrans(const float* __restrict__ Xg,
                                                   const float* __restrict__ Xp) {
    const int sel = blockIdx.y;
    const float* X = sel ? Xp : Xg;
    u8* Xb = g_Feat8 + (size_t)sel * N_ * D_;
    float* nr = sel ? g_np : g_ng;
    const int colofs = sel ? 0 : 4096;
    __shared__ u8 t8[128][33];
    const int r0 = blockIdx.x * 32;
    const int tx = threadIdx.x, ty = threadIdx.y;
    float a[4] = {0, 0, 0, 0};
    for (int c0 = 0; c0 < D_; c0 += 128) {
#pragma unroll
        for (int kk = 0; kk < 4; ++kk) {
            const int r = r0 + ty + kk * 8;
#pragma unroll
            for (int cc = 0; cc < 4; ++cc) {
                const int c = c0 + cc * 32 + tx;
                float v = X[(size_t)r * D_ + c];
                a[kk] += v * v;
                u8 b8 = cvt1fp8(v);
                Xb[(size_t)r * D_ + c] = b8;
                t8[cc * 32 + tx][ty + kk * 8] = b8;
            }
        }
        __syncthreads();
#pragma unroll
        for (int qq = 0; qq < 16; ++qq) {
            const int q = qq * 8 + ty;
            g_BT[(size_t)(c0 + q) * (2 * N_) + colofs + r0 + tx] = t8[q][tx];
        }
        __syncthreads();
    }
#pragma unroll
    for (int j = 0; j < 4; ++j) {
        float v = a[j];
        v += __shfl_xor(v, 1, 64);
        v += __shfl_xor(v, 2, 64);
        v += __shfl_xor(v, 4, 64);
        v += __shfl_xor(v, 8, 64);
        v += __shfl_xor(v, 16, 64);
        if (tx == 0) nr[r0 + ty + 8 * j] = v;
    }
}

// ---------------- init min arrays ----------------
__global__ __launch_bounds__(256) void k_mininit() {
    int idx = blockIdx.x * 256 + threadIdx.x;
    if (idx < N_) g_rminp[idx] = 1e30f;
    else if (idx < 2 * N_) g_rminn[idx - N_] = 1e30f;
    else g_cminp[idx - 2 * N_] = 1e30f;
}

// ---------------- S-GEMM (MX fp8, K=128, unit scales) — R16-proven ----------
__global__ __launch_bounds__(512, 1) void k_gemmS() {
    constexpr int NF = 4;
    constexpr int Kb = D_;
    constexpr int nT = Kb >> 7;       // 24 super-tiles

    __shared__ u8 lds8[131072];       // A: 2x32KB @0 ; B: 2x32KB @65536

    const int nwg = gridDim.x;
    const int cpx = nwg >> 3;
    const int bid = blockIdx.x;
    const int swz = (bid & 7) * cpx + (bid >> 3);

    int i0, j0, jfeat;
    bool isSn = false, isDiag = false;
    if (swz < 256) {
        const int by = swz >> 4, bx = swz & 15;
        i0 = by * 256; j0 = bx * 256; jfeat = 4096 + j0;
    } else {
        int t = swz - 256, by = 0;
        while (t >= 16 - by) { t -= 16 - by; ++by; }
        const int bx = by + t;
        i0 = by * 256; j0 = bx * 256; jfeat = j0;
        isSn = true; isDiag = (bx == by);
    }

    const int tid = threadIdx.x;
    const int l = tid & 63, w = tid >> 6;
    const int wr = w >> 2, wc = w & 3;
    const int fr = l & 15, kg = l >> 4;

    const int lrow = w * 8 + (l >> 3);
    const int schunk = ((l & 7) ^ (l >> 3)) * 16;
    const u8* aB = g_Feat8 + (size_t)(i0 + lrow) * Kb + schunk;
    const u8* bB = g_Feat8 + (size_t)(jfeat + lrow) * Kb + schunk;

    f32x4 acc[8][NF] = {};

#define STAGE_S(T) {                                                         \
        const int sA_ = ((T) & 1) * 32768;                                   \
        const int sB_ = 65536 + ((T) & 1) * 32768;                           \
        _Pragma("unroll") for (int a = 0; a < 4; ++a)                        \
            gload16(aB + (size_t)(a * 64) * Kb + (T) * 128,                  \
                    lds8 + sA_ + (w * 8 + a * 64) * 128);                    \
        _Pragma("unroll") for (int b = 0; b < 4; ++b)                        \
            gload16(bB + (size_t)(b * 64) * Kb + (T) * 128,                  \
                    lds8 + sB_ + (w * 8 + b * 64) * 128);                    \
    }

#define RDFRAG_S(dst, slotbase, ROW) {                                       \
        const char* base_ = (const char*)lds8 + (slotbase) + (ROW) * 128;    \
        i32x4v lo_ = *(const i32x4v*)(base_ + (((kg * 2) ^ ((ROW) & 7)) * 16));     \
        i32x4v hi_ = *(const i32x4v*)(base_ + (((kg * 2 + 1) ^ ((ROW) & 7)) * 16)); \
        dst = __builtin_shufflevector(lo_, hi_, 0, 1, 2, 3, 4, 5, 6, 7);     \
    }

    STAGE_S(0);

    for (int T = 0; T < nT; ++T) {
        const int sA = (T & 1) * 32768;
        const int sB = 65536 + (T & 1) * 32768;
        asm volatile("s_waitcnt vmcnt(0)" ::: "memory");
        asm volatile("s_barrier" ::: "memory");

        i32x8v av[4], bv[NF];
#pragma unroll
        for (int m = 0; m < 4; ++m) {
            int row = wr * 128 + m * 16 + fr;
            RDFRAG_S(av[m], sA, row);
        }
#pragma unroll
        for (int n = 0; n < NF; ++n) {
            int row = wc * (NF * 16) + n * 16 + fr;
            RDFRAG_S(bv[n], sB, row);
        }
        { int Tn = T + 1; if (Tn > nT - 1) Tn = nT - 1; STAGE_S(Tn); }

        asm volatile("s_waitcnt lgkmcnt(0)" ::: "memory");
        __builtin_amdgcn_sched_barrier(0);
        __builtin_amdgcn_s_setprio(1);
#pragma unroll
        for (int m = 0; m < 4; ++m)
#pragma unroll
            for (int n = 0; n < NF; ++n)
                acc[m][n] = __builtin_amdgcn_mfma_scale_f32_16x16x128_f8f6f4(
                    av[m], bv[n], acc[m][n], 0, 0, 0, 0x7F7F7F7F, 0, 0x7F7F7F7F);
        __builtin_amdgcn_s_setprio(0);

#pragma unroll
        for (int m = 0; m < 4; ++m) {
            int row = wr * 128 + (4 + m) * 16 + fr;
            RDFRAG_S(av[m], sA, row);
        }
        asm volatile("s_waitcnt lgkmcnt(0)" ::: "memory");
        __builtin_amdgcn_sched_barrier(0);
        __builtin_amdgcn_s_setprio(1);
#pragma unroll
        for (int m = 0; m < 4; ++m)
#pragma unroll
            for (int n = 0; n < NF; ++n)
                acc[4 + m][n] = __builtin_amdgcn_mfma_scale_f32_16x16x128_f8f6f4(
                    av[m], bv[n], acc[4 + m][n], 0, 0, 0, 0x7F7F7F7F, 0, 0x7F7F7F7F);
        __builtin_amdgcn_s_setprio(0);
    }
#undef STAGE_S
#undef RDFRAG_S

    const int fq = l >> 4;
    float* Sd = isSn ? g_Sn : g_Sp;
    const float* nb = isSn ? g_ng : g_np;
    float cmin[NF];
#pragma unroll
    for (int n = 0; n < NF; ++n) cmin[n] = 1e30f;

#pragma unroll
    for (int m = 0; m < 8; ++m) {
        const int row0 = i0 + wr * 128 + m * 16 + fq * 4;
        float rmin[4] = {1e30f, 1e30f, 1e30f, 1e30f};
#pragma unroll
        for (int n = 0; n < NF; ++n) {
            const int col = j0 + wc * 64 + n * 16 + fr;
            const float nbc = nb[col];
            f32x4 dm;
#pragma unroll
            for (int r = 0; r < 4; ++r) {
                const int row = row0 + r;
                float d2 = g_ng[row] + nbc - 2.f * acc[m][n][r];
                float d = sqrtf(fmaxf(d2, 0.f));
                if (isSn && col == row) d += 1000000.0f;
                Sd[(size_t)row * 4096 + col] = d;
                dm[r] = d;
                rmin[r] = fminf(rmin[r], d);
                cmin[n] = fminf(cmin[n], d);
            }
            if (isSn && !isDiag)
                *(f32x4*)&g_Sn[(size_t)col * 4096 + row0] = dm;
        }
#pragma unroll
        for (int r = 0; r < 4; ++r) {
            float v = rmin[r];
            v = fminf(v, __shfl_xor(v, 1, 64));
            v = fminf(v, __shfl_xor(v, 2, 64));
            v = fminf(v, __shfl_xor(v, 4, 64));
            v = fminf(v, __shfl_xor(v, 8, 64));
            if (fr == 0) atomicMinF(isSn ? &g_rminn[row0 + r] : &g_rminp[row0 + r], v);
        }
    }
#pragma unroll
    for (int n = 0; n < NF; ++n) {
        float v = cmin[n];
        v = fminf(v, __shfl_xor(v, 16, 64));
        v = fminf(v, __shfl_xor(v, 32, 64));
        if (kg == 0) {
            const int col = j0 + wc * 64 + n * 16 + fr;
            atomicMinF(isSn ? &g_rminn[col] : &g_cminp[col], v);
        }
    }
}

// ---------------- V-GEMM (MX fp8 K=128), BM=128, 2 blocks/CU ----------------
// BM=128, BN=192 (NF=3); 8 waves (2Mx4N), wave tile 64x48, acc[4][3].
// LDS 80KB: A ring 2x16KB @0, B ring 2x24KB @32768 -> two blocks co-resident
// (160KB LDS/CU); co-resident blocks hide each other's vmcnt(0) stalls (m114).
// Staging 5 gloads/wave/tile (A 2 pieces, B 3); same lane-map/swizzle as R13.
// GRAM=0: grid 1024 (tau = swz>>9, 2 rounds); writes V_tau.
// GRAM=1: grid 512, tau=2; V_2 in-reg; Gram partials vs V_0/V_1.
template <int GRAM>
__global__ __launch_bounds__(512, 1) void k_gemmV() {
    constexpr int NF = 3;
    constexpr int Kb = 2 * N_;        // 8192 bytes
    constexpr int nT = Kb >> 7;       // 64 super-tiles

    __shared__ u8 lds8[81920];        // A: 2x16KB @0 ; B: 2x24KB @32768

    const int nwg = gridDim.x;
    const int cpx = nwg >> 3;
    const int bid = blockIdx.x;
    const int swz = (bid & 7) * cpx + (bid >> 3);
    const int tsel = GRAM ? 2 : (swz >> 9);
    const int tile = GRAM ? swz : (swz & 511);
    const int by = tile >> 4, bx = tile & 15;
    const int i0 = by * 128, j0 = bx * (NF * 64);
    const u8* Am = g_Wall + (size_t)tsel * N_ * 2 * N_;
    const u8* Bm = g_BT;

    const int tid = threadIdx.x;
    const int l = tid & 63, w = tid >> 6;
    const int wr = w >> 2, wc = w & 3;
    const int fr = l & 15, kg = l >> 4;

    const int lrow = w * 8 + (l >> 3);
    const int schunk = ((l & 7) ^ (l >> 3)) * 16;
    const u8* aB = Am + (size_t)(i0 + lrow) * Kb + schunk;
    const u8* bB = Bm + (size_t)(j0 + lrow) * Kb + schunk;

    f32x4 acc[4][NF] = {};

#define STAGE_T(T) {                                                         \
        const int sA_ = ((T) & 1) * 16384;                                   \
        const int sB_ = 32768 + ((T) & 1) * 24576;                           \
        _Pragma("unroll") for (int a = 0; a < 2; ++a)                        \
            gload16(aB + (size_t)(a * 64) * Kb + (T) * 128,                  \
                    lds8 + sA_ + (w * 8 + a * 64) * 128);                    \
        _Pragma("unroll") for (int b = 0; b < 3; ++b)                        \
            gload16(bB + (size_t)(b * 64) * Kb + (T) * 128,                  \
                    lds8 + sB_ + (w * 8 + b * 64) * 128);                    \
    }

#define RDFRAG(dst, slotbase, ROW) {                                         \
        const char* base_ = (const char*)lds8 + (slotbase) + (ROW) * 128;    \
        i32x4v lo_ = *(const i32x4v*)(base_ + (((kg * 2) ^ ((ROW) & 7)) * 16));     \
        i32x4v hi_ = *(const i32x4v*)(base_ + (((kg * 2 + 1) ^ ((ROW) & 7)) * 16)); \
        dst = __builtin_shufflevector(lo_, hi_, 0, 1, 2, 3, 4, 5, 6, 7);     \
    }

    STAGE_T(0);

    for (int T = 0; T < nT; ++T) {
        const int sA = (T & 1) * 16384;
        const int sB = 32768 + (T & 1) * 24576;
        asm volatile("s_waitcnt vmcnt(0)" ::: "memory");
        asm volatile("s_barrier" ::: "memory");

        i32x8v av[4], bv[NF];
#pragma unroll
        for (int m = 0; m < 4; ++m) {
            int row = wr * 64 + m * 16 + fr;
            RDFRAG(av[m], sA, row);
        }
#pragma unroll
        for (int n = 0; n < NF; ++n) {
            int row = wc * (NF * 16) + n * 16 + fr;
            RDFRAG(bv[n], sB, row);
        }
        { int Tn = T + 1; if (Tn > nT - 1) Tn = nT - 1; STAGE_T(Tn); }

        asm volatile("s_waitcnt lgkmcnt(0)" ::: "memory");
        __builtin_amdgcn_sched_barrier(0);
        __builtin_amdgcn_s_setprio(1);
#pragma unroll
        for (int m = 0; m < 4; ++m)
#pragma unroll
            for (int n = 0; n < NF; ++n)
                acc[m][n] = __builtin_amdgcn_mfma_scale_f32_16x16x128_f8f6f4(
                    av[m], bv[n], acc[m][n], 0, 0, 0, 0x7F7F7F7F, 0, 0x7F7F7F7F);
        __builtin_amdgcn_s_setprio(0);
    }
#undef STAGE_T
#undef RDFRAG

    const int fq = l >> 4;
    if (GRAM == 0) {
        float* Vout = g_Vall + (size_t)tsel * N_ * D_;
#pragma unroll
        for (int m = 0; m < 4; ++m)
#pragma unroll
            for (int n = 0; n < NF; ++n)
#pragma unroll
                for (int r = 0; r < 4; ++r) {
                    int row = i0 + wr * 64 + m * 16 + fq * 4 + r;
                    int col = j0 + wc * (NF * 16) + n * 16 + fr;
                    Vout[(size_t)row * D_ + col] = acc[m][n][r];
                }
    } else {
        const float* V0 = g_Vall;
        const float* V1 = g_Vall + (size_t)N_ * D_;
        float g00 = 0, g11 = 0, g22 = 0, g01 = 0, g02 = 0, g12 = 0;
#pragma unroll
        for (int m = 0; m < 4; ++m)
#pragma unroll
            for (int n = 0; n < NF; ++n)
#pragma unroll
                for (int r = 0; r < 4; ++r) {
                    int row = i0 + wr * 64 + m * 16 + fq * 4 + r;
                    int col = j0 + wc * (NF * 16) + n * 16 + fr;
                    size_t idx = (size_t)row * D_ + col;
                    float v2 = acc[m][n][r];
                    float v0 = V0[idx], v1 = V1[idx];
                    g00 += v0 * v0; g11 += v1 * v1; g22 += v2 * v2;
                    g01 += v0 * v1; g02 += v0 * v2; g12 += v1 * v2;
                }
        asm volatile("s_waitcnt vmcnt(0)" ::: "memory");
        __syncthreads();
        float gv[6] = {g00, g11, g22, g01, g02, g12};
        float* redf = (float*)lds8;
#pragma unroll
        for (int k = 0; k < 6; ++k) {
            float v = gv[k];
#pragma unroll
            for (int s = 32; s; s >>= 1) v += __shfl_down(v, s, 64);
            if (l == 0) redf[w * 6 + k] = v;
        }
        __syncthreads();
        if (tid < 6) {
            float s = 0;
#pragma unroll
            for (int k = 0; k < 8; ++k) s += redf[k * 6 + tid];
            g_part6[tid * 512 + bid] = s;
        }
    }
}

// ---------------- per-row exp-sums (exp-chain) ----------------
__global__ __launch_bounds__(256) void k_rowstat() {
    __shared__ float red[6][4];
    int i = blockIdx.x;
    float rd = fminf(g_rminp[i], g_rminn[i]);
    float rnn = g_rminn[i];
    const float4* rp4 = (const float4*)(g_Sp + (size_t)i * N_);
    const float4* rn4 = (const float4*)(g_Sn + (size_t)i * N_);
    float v[6] = {0, 0, 0, 0, 0, 0};
    for (int c = threadIdx.x; c < 1024; c += 256) {
        float4 a = rp4[c], b = rn4[c];
#pragma unroll
        for (int e = 0; e < 4; ++e) {
            float dp = (&a.x)[e], dn = (&b.x)[e];
            {
                EXPCHAIN((rd - dp) * 5.f, e5, e20, e50)
                v[0] += e50; v[1] += e20; v[2] += e5;
            }
            {
                EXPCHAIN((rd - dn) * 5.f, e5, e20, e50)
                v[0] += e50; v[1] += e20; v[2] += e5;
            }
            {
                EXPCHAIN((rnn - dn) * 5.f, e5, e20, e50)
                v[3] += e50; v[4] += e20; v[5] += e5;
            }
        }
    }
    int l = threadIdx.x & 63, w = threadIdx.x >> 6;
#pragma unroll
    for (int k = 0; k < 6; ++k)
#pragma unroll
        for (int s = 32; s; s >>= 1) v[k] += __shfl_down(v[k], s, 64);
    if (l == 0)
#pragma unroll
        for (int k = 0; k < 6; ++k) red[k][w] = v[k];
    __syncthreads();
    int t = threadIdx.x;
    if (t < 6) {
        float s = red[t][0] + red[t][1] + red[t][2] + red[t][3];
        if (t < 3) g_R[t * N_ + i] = rsqrtf(s);
        else g_Cn[(t - 3) * N_ + i] = rsqrtf(s);
    }
}

// ---------------- column exp-sums of d_pos (exp-chain) ----------------
__global__ __launch_bounds__(256) void k_colexp() {
    int j = blockIdx.x * 256 + threadIdx.x;
    int ch = blockIdx.y;
    int i0 = ch * 512;
    float cm = g_cminp[j];
    float a0 = 0, a1 = 0, a2 = 0;
    for (int i = i0; i < i0 + 512; ++i) {
        EXPCHAIN((cm - g_Sp[(size_t)i * N_ + j]) * 5.f, e5, e20, e50)
        a0 += e50; a1 += e20; a2 += e5;
    }
    g_Cpart[(size_t)ch * (3 * N_) + 0 * N_ + j] = a0;
    g_Cpart[(size_t)ch * (3 * N_) + 1 * N_ + j] = a1;
    g_Cpart[(size_t)ch * (3 * N_) + 2 * N_ + j] = a2;
}
__global__ __launch_bounds__(256) void k_colreduce() {
    int idx = blockIdx.x * 256 + threadIdx.x;
    float s = 0;
#pragma unroll
    for (int ch = 0; ch < 8; ++ch) s += g_Cpart[(size_t)ch * (3 * N_) + idx];
    g_Cp[idx] = rsqrtf(s);
}

// ---------------- fused rowsumA + W generation (exp-chain, fp8 out) ----------
__global__ __launch_bounds__(256) void k_wfuse() {
    __shared__ float sp[4096];
    __shared__ float sn[4096];
    __shared__ float red[6][4];
    __shared__ float bc[6];
    int i = blockIdx.x;
    float rd = fminf(g_rminp[i], g_rminn[i]);
    const float4* rp4 = (const float4*)(g_Sp + (size_t)i * N_);
    const float4* rn4 = (const float4*)(g_Sn + (size_t)i * N_);
    for (int c = threadIdx.x; c < 1024; c += 256) {
        ((float4*)sp)[c] = rp4[c];
        ((float4*)sn)[c] = rn4[c];
    }
    __syncthreads();
    const float iR0 = g_R[i], iR1 = g_R[N_ + i], iR2 = g_R[2 * N_ + i];
    float v[6] = {0, 0, 0, 0, 0, 0};
    for (int j = threadIdx.x; j < 4096; j += 256) {
        {
            EXPCHAIN((0.5f * (rd + g_cminp[j]) - sp[j]) * 5.f, e5, e20, e50)
            v[0] += e50 * g_Cp[j];
            v[1] += e20 * g_Cp[N_ + j];
            v[2] += e5 * g_Cp[2 * N_ + j];
        }
        {
            EXPCHAIN((0.5f * (rd + g_rminn[j]) - sn[j]) * 5.f, e5, e20, e50)
            v[3] += e50 * g_Cn[j];
            v[4] += e20 * g_Cn[N_ + j];
            v[5] += e5 * g_Cn[2 * N_ + j];
        }
    }
    int l = threadIdx.x & 63, w = threadIdx.x >> 6;
#pragma unroll
    for (int k = 0; k < 6; ++k)
#pragma unroll
        for (int s = 32; s; s >>= 1) v[k] += __shfl_down(v[k], s, 64);
    if (l == 0)
#pragma unroll
        for (int k = 0; k < 6; ++k) red[k][w] = v[k];
    __syncthreads();
    if (threadIdx.x < 6) {
        int t = threadIdx.x;
        float s = red[t][0] + red[t][1] + red[t][2] + red[t][3];
        float iR = (t % 3 == 0) ? iR0 : ((t % 3 == 1) ? iR1 : iR2);
        bc[t] = s * iR;
    }
    __syncthreads();
    const float sp0 = bc[0], sp1 = bc[1], sp2 = bc[2];
    const float sn0 = bc[3], sn1 = bc[4], sn2 = bc[5];
    for (int gq = threadIdx.x; gq < 512; gq += 256) {
        int j0 = gq * 8;
        float fp[3][8], fn[3][8];
#pragma unroll
        for (int e = 0; e < 8; ++e) {
            int j = j0 + e;
            {
                EXPCHAIN((0.5f * (rd + g_cminp[j]) - sp[j]) * 5.f, e5, e20, e50)
                fp[0][e] = e50 * iR0 * g_Cp[j] * sn0;
                fp[1][e] = e20 * iR1 * g_Cp[N_ + j] * sn1;
                fp[2][e] = e5 * iR2 * g_Cp[2 * N_ + j] * sn2;
            }
            {
                EXPCHAIN((0.5f * (rd + g_rminn[j]) - sn[j]) * 5.f, e5, e20, e50)
                fn[0][e] = -(e50 * iR0 * g_Cn[j] * sp0);
                fn[1][e] = -(e20 * iR1 * g_Cn[N_ + j] * sp1);
                fn[2][e] = -(e5 * iR2 * g_Cn[2 * N_ + j] * sp2);
            }
        }
#pragma unroll
        for (int t = 0; t < 3; ++t) {
            u16 op[4], on[4];
#pragma unroll
            for (int e2 = 0; e2 < 4; ++e2) {
                op[e2] = cvt2fp8(fp[t][2 * e2], fp[t][2 * e2 + 1]);
                on[e2] = cvt2fp8(fn[t][2 * e2], fn[t][2 * e2 + 1]);
            }
            *(uint2*)&g_Wall[((size_t)t * N_ + i) * (2 * N_) + j0] = *(const uint2*)op;
            *(uint2*)&g_Wall[((size_t)t * N_ + i) * (2 * N_) + 4096 + j0] = *(const uint2*)on;
        }
    }
}

// ---------------- finalize: m from Gram matrix ----------------
__global__ __launch_bounds__(256) void k_finalize(float* out) {
    float g[6];
#pragma unroll
    for (int k = 0; k < 6; ++k) {
        g[k] = blockSum256(g_part6[k * 512 + threadIdx.x] +
                           g_part6[k * 512 + 256 + threadIdx.x]);
    }
    if (threadIdx.x == 0) {
        const float nd = (float)N_ * (float)D_;
        float s0 = rsqrtf(g[0] / nd + 1e-8f);
        float s1 = rsqrtf(g[1] / nd + 1e-8f);
        float s2 = rsqrtf(g[2] / nd + 1e-8f);
        float m = (g[0] * s0 * s0 + g[1] * s1 * s1 + g[2] * s2 * s2 +
                   2.f * (g[3] * s0 * s1 + g[4] * s0 * s2 + g[5] * s1 * s2)) / nd;
        out[0] = m / (m + 1e-8f);
    }
}

// ---------------- host orchestration ----------------
extern "C" void kernel_launch(void* const* d_in, const int* in_sizes, int n_in,
                              void* d_out, int out_size, void* d_ws, size_t ws_size,
                              hipStream_t stream) {
    const float* xg = (const float*)d_in[0];
    const float* xp = (const float*)d_in[1];
    float* out = (float*)d_out;

    k_mininit<<<48, 256, 0, stream>>>();
    k_convtrans<<<dim3(N_ / 32, 2), dim3(32, 8), 0, stream>>>(xg, xp);

    k_gemmS<<<392, 512, 0, stream>>>();      // MX fp8: dist + mins

    k_rowstat<<<N_, 256, 0, stream>>>();
    k_colexp<<<dim3(N_ / 256, 8), 256, 0, stream>>>();
    k_colreduce<<<3 * N_ / 256, 256, 0, stream>>>();
    k_wfuse<<<N_, 256, 0, stream>>>();

    k_gemmV<0><<<1024, 512, 0, stream>>>();  // V_0, V_1 (BM=128, 2 blk/CU)
    k_gemmV<1><<<512, 512, 0, stream>>>();   // V_2 in-reg + Gram partials

    k_finalize<<<1, 256, 0, stream>>>(out);
}

// Round 19
// 704.916 us; speedup vs baseline: 1.1742x; 1.1742x over previous
//
#include <hip/hip_runtime.h>
#include <hip/hip_bf16.h>

typedef unsigned short u16;
typedef unsigned char u8;
typedef float f32x4 __attribute__((ext_vector_type(4)));
typedef int i32x4v __attribute__((ext_vector_type(4)));
typedef int i32x8v __attribute__((ext_vector_type(8)));

#define N_ 4096
#define D_ 3072

// ---------------- static device workspace ----------------
__device__ __align__(256) u8   g_Feat8[(size_t)2 * N_ * D_];     // fp8 [G rows ; P rows]
__device__ __align__(256) u8   g_BT[(size_t)(D_ + 64) * 2 * N_]; // fp8 [3072(+64)][8192] = [PbT | GbT]
__device__ __align__(256) u8   g_Wall[(size_t)3 * N_ * 2 * N_];  // fp8 [tau][4096][8192] = [Wp | -Wn]
__device__ __align__(256) float g_Sp[(size_t)N_ * N_];           // dist_pos
__device__ __align__(256) float g_Sn[(size_t)N_ * N_];           // dist_neg (+diag mask)
__device__ __align__(256) float g_Vall[(size_t)2 * N_ * D_];     // V_0, V_1 only (V_2 never stored)
__device__ float g_ng[N_], g_np[N_];
__device__ float g_rminp[N_], g_rminn[N_], g_cminp[N_];          // via atomicMin in S-GEMM
__device__ float g_R [3 * N_];    // rsqrt(row exp-sums)
__device__ float g_Cp[3 * N_];    // rsqrt(col exp-sums, pos)
__device__ float g_Cn[3 * N_];    // rsqrt(col exp-sums, neg = row sums by symmetry)
__device__ float g_Cpart[8 * 3 * N_];
__device__ float g_part6[6 * 256];   // Gram partials G00,G11,G22,G01,G02,G12

// ---------------- helpers ----------------
__device__ __forceinline__ u16 cvt2fp8(float a, float b) {
    return (u16)(__builtin_amdgcn_cvt_pk_fp8_f32(a, b, 0, false) & 0xffff);
}
__device__ __forceinline__ u8 cvt1fp8(float a) {
    return (u8)(__builtin_amdgcn_cvt_pk_fp8_f32(a, a, 0, false) & 0xff);
}

// exp chain: from e1 = exp(5x) derive e20 = e1^4, e50 = e1^10 (4 muls)
#define EXPCHAIN(x5, E5, E20, E50) \
    float E5 = __expf(x5); float E5##_2 = E5 * E5; float E20 = E5##_2 * E5##_2; \
    float E50 = E20 * E20 * E5##_2;

__device__ __forceinline__ float blockSum256(float v) {
    __shared__ float red[4];
#pragma unroll
    for (int s = 32; s; s >>= 1) v += __shfl_down(v, s, 64);
    int l = threadIdx.x & 63, w = threadIdx.x >> 6;
    if (l == 0) red[w] = v;
    __syncthreads();
    float r = red[0] + red[1] + red[2] + red[3];
    __syncthreads();
    return r;
}

__device__ __forceinline__ void gload16(const void* g, void* lds) {
    __builtin_amdgcn_global_load_lds(
        (const __attribute__((address_space(1))) void*)g,
        (__attribute__((address_space(3))) void*)lds, 16, 0, 0);
}

__device__ __forceinline__ void atomicMinF(float* p, float v) {
    atomicMin((unsigned int*)p, __float_as_uint(v));   // exact for v >= 0
}

// ---- fused convert(fp8) + row norms + transpose + min-array init ----
// grid (N_/32, 2). blockIdx.y==0 blocks also init the 3*N_ min slots (12288 =
// 128 blocks x 96) before their main loop; convtrans completes before gemmS.
__global__ __launch_bounds__(256) void k_convtrans(const float* __restrict__ Xg,
                                                   const float* __restrict__ Xp) {
    const int sel = blockIdx.y;
    const int tid256 = threadIdx.y * 32 + threadIdx.x;
    if (sel == 0 && tid256 < 96) {
        int idx = blockIdx.x * 96 + tid256;   // 0..12287
        if (idx < N_) g_rminp[idx] = 1e30f;
        else if (idx < 2 * N_) g_rminn[idx - N_] = 1e30f;
        else g_cminp[idx - 2 * N_] = 1e30f;
    }
    const float* X = sel ? Xp : Xg;
    u8* Xb = g_Feat8 + (size_t)sel * N_ * D_;
    float* nr = sel ? g_np : g_ng;
    const int colofs = sel ? 0 : 4096;
    __shared__ u8 t8[128][33];
    const int r0 = blockIdx.x * 32;
    const int tx = threadIdx.x, ty = threadIdx.y;
    float a[4] = {0, 0, 0, 0};
    for (int c0 = 0; c0 < D_; c0 += 128) {
#pragma unroll
        for (int kk = 0; kk < 4; ++kk) {
            const int r = r0 + ty + kk * 8;
#pragma unroll
            for (int cc = 0; cc < 4; ++cc) {
                const int c = c0 + cc * 32 + tx;
                float v = X[(size_t)r * D_ + c];
                a[kk] += v * v;
                u8 b8 = cvt1fp8(v);
                Xb[(size_t)r * D_ + c] = b8;
                t8[cc * 32 + tx][ty + kk * 8] = b8;
            }
        }
        __syncthreads();
#pragma unroll
        for (int qq = 0; qq < 16; ++qq) {
            const int q = qq * 8 + ty;
            g_BT[(size_t)(c0 + q) * (2 * N_) + colofs + r0 + tx] = t8[q][tx];
        }
        __syncthreads();
    }
#pragma unroll
    for (int j = 0; j < 4; ++j) {
        float v = a[j];
        v += __shfl_xor(v, 1, 64);
        v += __shfl_xor(v, 2, 64);
        v += __shfl_xor(v, 4, 64);
        v += __shfl_xor(v, 8, 64);
        v += __shfl_xor(v, 16, 64);
        if (tx == 0) nr[r0 + ty + 8 * j] = v;
    }
}

// ---------------- S-GEMM (MX fp8, K=128, unit scales) — R16-proven ----------
__global__ __launch_bounds__(512, 1) void k_gemmS() {
    constexpr int NF = 4;
    constexpr int Kb = D_;
    constexpr int nT = Kb >> 7;       // 24 super-tiles

    __shared__ u8 lds8[131072];       // A: 2x32KB @0 ; B: 2x32KB @65536

    const int nwg = gridDim.x;
    const int cpx = nwg >> 3;
    const int bid = blockIdx.x;
    const int swz = (bid & 7) * cpx + (bid >> 3);

    int i0, j0, jfeat;
    bool isSn = false, isDiag = false;
    if (swz < 256) {
        const int by = swz >> 4, bx = swz & 15;
        i0 = by * 256; j0 = bx * 256; jfeat = 4096 + j0;
    } else {
        int t = swz - 256, by = 0;
        while (t >= 16 - by) { t -= 16 - by; ++by; }
        const int bx = by + t;
        i0 = by * 256; j0 = bx * 256; jfeat = j0;
        isSn = true; isDiag = (bx == by);
    }

    const int tid = threadIdx.x;
    const int l = tid & 63, w = tid >> 6;
    const int wr = w >> 2, wc = w & 3;
    const int fr = l & 15, kg = l >> 4;

    const int lrow = w * 8 + (l >> 3);
    const int schunk = ((l & 7) ^ (l >> 3)) * 16;
    const u8* aB = g_Feat8 + (size_t)(i0 + lrow) * Kb + schunk;
    const u8* bB = g_Feat8 + (size_t)(jfeat + lrow) * Kb + schunk;

    f32x4 acc[8][NF] = {};

#define STAGE_S(T) {                                                         \
        const int sA_ = ((T) & 1) * 32768;                                   \
        const int sB_ = 65536 + ((T) & 1) * 32768;                           \
        _Pragma("unroll") for (int a = 0; a < 4; ++a)                        \
            gload16(aB + (size_t)(a * 64) * Kb + (T) * 128,                  \
                    lds8 + sA_ + (w * 8 + a * 64) * 128);                    \
        _Pragma("unroll") for (int b = 0; b < 4; ++b)                        \
            gload16(bB + (size_t)(b * 64) * Kb + (T) * 128,                  \
                    lds8 + sB_ + (w * 8 + b * 64) * 128);                    \
    }

#define RDFRAG_S(dst, slotbase, ROW) {                                       \
        const char* base_ = (const char*)lds8 + (slotbase) + (ROW) * 128;    \
        i32x4v lo_ = *(const i32x4v*)(base_ + (((kg * 2) ^ ((ROW) & 7)) * 16));     \
        i32x4v hi_ = *(const i32x4v*)(base_ + (((kg * 2 + 1) ^ ((ROW) & 7)) * 16)); \
        dst = __builtin_shufflevector(lo_, hi_, 0, 1, 2, 3, 4, 5, 6, 7);     \
    }

    STAGE_S(0);

    for (int T = 0; T < nT; ++T) {
        const int sA = (T & 1) * 32768;
        const int sB = 65536 + (T & 1) * 32768;
        asm volatile("s_waitcnt vmcnt(0)" ::: "memory");
        asm volatile("s_barrier" ::: "memory");

        i32x8v av[4], bv[NF];
#pragma unroll
        for (int m = 0; m < 4; ++m) {
            int row = wr * 128 + m * 16 + fr;
            RDFRAG_S(av[m], sA, row);
        }
#pragma unroll
        for (int n = 0; n < NF; ++n) {
            int row = wc * (NF * 16) + n * 16 + fr;
            RDFRAG_S(bv[n], sB, row);
        }
        { int Tn = T + 1; if (Tn > nT - 1) Tn = nT - 1; STAGE_S(Tn); }

        asm volatile("s_waitcnt lgkmcnt(0)" ::: "memory");
        __builtin_amdgcn_sched_barrier(0);
        __builtin_amdgcn_s_setprio(1);
#pragma unroll
        for (int m = 0; m < 4; ++m)
#pragma unroll
            for (int n = 0; n < NF; ++n)
                acc[m][n] = __builtin_amdgcn_mfma_scale_f32_16x16x128_f8f6f4(
                    av[m], bv[n], acc[m][n], 0, 0, 0, 0x7F7F7F7F, 0, 0x7F7F7F7F);
        __builtin_amdgcn_s_setprio(0);

#pragma unroll
        for (int m = 0; m < 4; ++m) {
            int row = wr * 128 + (4 + m) * 16 + fr;
            RDFRAG_S(av[m], sA, row);
        }
        asm volatile("s_waitcnt lgkmcnt(0)" ::: "memory");
        __builtin_amdgcn_sched_barrier(0);
        __builtin_amdgcn_s_setprio(1);
#pragma unroll
        for (int m = 0; m < 4; ++m)
#pragma unroll
            for (int n = 0; n < NF; ++n)
                acc[4 + m][n] = __builtin_amdgcn_mfma_scale_f32_16x16x128_f8f6f4(
                    av[m], bv[n], acc[4 + m][n], 0, 0, 0, 0x7F7F7F7F, 0, 0x7F7F7F7F);
        __builtin_amdgcn_s_setprio(0);
    }
#undef STAGE_S
#undef RDFRAG_S

    const int fq = l >> 4;
    float* Sd = isSn ? g_Sn : g_Sp;
    const float* nb = isSn ? g_ng : g_np;
    float cmin[NF];
#pragma unroll
    for (int n = 0; n < NF; ++n) cmin[n] = 1e30f;

#pragma unroll
    for (int m = 0; m < 8; ++m) {
        const int row0 = i0 + wr * 128 + m * 16 + fq * 4;
        float rmin[4] = {1e30f, 1e30f, 1e30f, 1e30f};
#pragma unroll
        for (int n = 0; n < NF; ++n) {
            const int col = j0 + wc * 64 + n * 16 + fr;
            const float nbc = nb[col];
            f32x4 dm;
#pragma unroll
            for (int r = 0; r < 4; ++r) {
                const int row = row0 + r;
                float d2 = g_ng[row] + nbc - 2.f * acc[m][n][r];
                float d = sqrtf(fmaxf(d2, 0.f));
                if (isSn && col == row) d += 1000000.0f;
                Sd[(size_t)row * 4096 + col] = d;
                dm[r] = d;
                rmin[r] = fminf(rmin[r], d);
                cmin[n] = fminf(cmin[n], d);
            }
            if (isSn && !isDiag)
                *(f32x4*)&g_Sn[(size_t)col * 4096 + row0] = dm;
        }
#pragma unroll
        for (int r = 0; r < 4; ++r) {
            float v = rmin[r];
            v = fminf(v, __shfl_xor(v, 1, 64));
            v = fminf(v, __shfl_xor(v, 2, 64));
            v = fminf(v, __shfl_xor(v, 4, 64));
            v = fminf(v, __shfl_xor(v, 8, 64));
            if (fr == 0) atomicMinF(isSn ? &g_rminn[row0 + r] : &g_rminp[row0 + r], v);
        }
    }
#pragma unroll
    for (int n = 0; n < NF; ++n) {
        float v = cmin[n];
        v = fminf(v, __shfl_xor(v, 16, 64));
        v = fminf(v, __shfl_xor(v, 32, 64));
        if (kg == 0) {
            const int col = j0 + wc * 64 + n * 16 + fr;
            atomicMinF(isSn ? &g_rminn[col] : &g_cminp[col], v);
        }
    }
}

// ---------------- V-GEMM (MX fp8 K=128, R13/R17-proven core, BM=256) --------
// GRAM=0: grid 512, tsel = swz>>8 in {0,1}; epilogue writes V_tsel.
// GRAM=1: grid 256, tsel = 2; V_2 stays in registers; epilogue reads back the
//   V_0/V_1 tiles and emits 6 per-block Gram partials.
template <int GRAM>
__global__ __launch_bounds__(512, 1) void k_gemmV() {
    constexpr int NF = 3;
    constexpr int Kb = 2 * N_;        // 8192 bytes
    constexpr int nT = Kb >> 7;       // 64 super-tiles

    __shared__ u8 lds8[114688];       // A: 2x32KB @0 ; B: 2x24KB @65536

    const int nwg = gridDim.x;
    const int cpx = nwg >> 3;
    const int bid = blockIdx.x;
    const int swz = (bid & 7) * cpx + (bid >> 3);
    const int tsel = GRAM ? 2 : (swz >> 8);
    const int tile = GRAM ? swz : (swz & 255);
    const int by = tile >> 4, bx = tile & 15;
    const int i0 = by * 256, j0 = bx * (NF * 64);
    const u8* Am = g_Wall + (size_t)tsel * N_ * 2 * N_;
    const u8* Bm = g_BT;

    const int tid = threadIdx.x;
    const int l = tid & 63, w = tid >> 6;
    const int wr = w >> 2, wc = w & 3;
    const int fr = l & 15, kg = l >> 4;

    const int lrow = w * 8 + (l >> 3);
    const int schunk = ((l & 7) ^ (l >> 3)) * 16;
    const u8* aB = Am + (size_t)(i0 + lrow) * Kb + schunk;
    const u8* bB = Bm + (size_t)(j0 + lrow) * Kb + schunk;

    f32x4 acc[8][NF] = {};

#define STAGE_T(T) {                                                         \
        const int sA_ = ((T) & 1) * 32768;                                   \
        const int sB_ = 65536 + ((T) & 1) * 24576;                           \
        _Pragma("unroll") for (int a = 0; a < 4; ++a)                        \
            gload16(aB + (size_t)(a * 64) * Kb + (T) * 128,                  \
                    lds8 + sA_ + (w * 8 + a * 64) * 128);                    \
        _Pragma("unroll") for (int b = 0; b < 3; ++b)                        \
            gload16(bB + (size_t)(b * 64) * Kb + (T) * 128,                  \
                    lds8 + sB_ + (w * 8 + b * 64) * 128);                    \
    }

#define RDFRAG(dst, slotbase, ROW) {                                         \
        const char* base_ = (const char*)lds8 + (slotbase) + (ROW) * 128;    \
        i32x4v lo_ = *(const i32x4v*)(base_ + (((kg * 2) ^ ((ROW) & 7)) * 16));     \
        i32x4v hi_ = *(const i32x4v*)(base_ + (((kg * 2 + 1) ^ ((ROW) & 7)) * 16)); \
        dst = __builtin_shufflevector(lo_, hi_, 0, 1, 2, 3, 4, 5, 6, 7);     \
    }

    STAGE_T(0);

    for (int T = 0; T < nT; ++T) {
        const int sA = (T & 1) * 32768;
        const int sB = 65536 + (T & 1) * 24576;
        asm volatile("s_waitcnt vmcnt(0)" ::: "memory");
        asm volatile("s_barrier" ::: "memory");

        i32x8v av[4], bv[NF];
#pragma unroll
        for (int m = 0; m < 4; ++m) {
            int row = wr * 128 + m * 16 + fr;
            RDFRAG(av[m], sA, row);
        }
#pragma unroll
        for (int n = 0; n < NF; ++n) {
            int row = wc * (NF * 16) + n * 16 + fr;
            RDFRAG(bv[n], sB, row);
        }
        { int Tn = T + 1; if (Tn > nT - 1) Tn = nT - 1; STAGE_T(Tn); }

        asm volatile("s_waitcnt lgkmcnt(0)" ::: "memory");
        __builtin_amdgcn_sched_barrier(0);
        __builtin_amdgcn_s_setprio(1);
#pragma unroll
        for (int m = 0; m < 4; ++m)
#pragma unroll
            for (int n = 0; n < NF; ++n)
                acc[m][n] = __builtin_amdgcn_mfma_scale_f32_16x16x128_f8f6f4(
                    av[m], bv[n], acc[m][n], 0, 0, 0, 0x7F7F7F7F, 0, 0x7F7F7F7F);
        __builtin_amdgcn_s_setprio(0);

#pragma unroll
        for (int m = 0; m < 4; ++m) {
            int row = wr * 128 + (4 + m) * 16 + fr;
            RDFRAG(av[m], sA, row);
        }
        asm volatile("s_waitcnt lgkmcnt(0)" ::: "memory");
        __builtin_amdgcn_sched_barrier(0);
        __builtin_amdgcn_s_setprio(1);
#pragma unroll
        for (int m = 0; m < 4; ++m)
#pragma unroll
            for (int n = 0; n < NF; ++n)
                acc[4 + m][n] = __builtin_amdgcn_mfma_scale_f32_16x16x128_f8f6f4(
                    av[m], bv[n], acc[4 + m][n], 0, 0, 0, 0x7F7F7F7F, 0, 0x7F7F7F7F);
        __builtin_amdgcn_s_setprio(0);
    }
#undef STAGE_T
#undef RDFRAG

    const int fq = l >> 4;
    if (GRAM == 0) {
        float* Vout = g_Vall + (size_t)tsel * N_ * D_;
#pragma unroll
        for (int m = 0; m < 8; ++m)
#pragma unroll
            for (int n = 0; n < NF; ++n)
#pragma unroll
                for (int r = 0; r < 4; ++r) {
                    int row = i0 + wr * 128 + m * 16 + fq * 4 + r;
                    int col = j0 + wc * (NF * 16) + n * 16 + fr;
                    Vout[(size_t)row * D_ + col] = acc[m][n][r];
                }
    } else {
        const float* V0 = g_Vall;
        const float* V1 = g_Vall + (size_t)N_ * D_;
        float g00 = 0, g11 = 0, g22 = 0, g01 = 0, g02 = 0, g12 = 0;
#pragma unroll
        for (int m = 0; m < 8; ++m)
#pragma unroll
            for (int n = 0; n < NF; ++n)
#pragma unroll
                for (int r = 0; r < 4; ++r) {
                    int row = i0 + wr * 128 + m * 16 + fq * 4 + r;
                    int col = j0 + wc * (NF * 16) + n * 16 + fr;
                    size_t idx = (size_t)row * D_ + col;
                    float v2 = acc[m][n][r];
                    float v0 = V0[idx], v1 = V1[idx];
                    g00 += v0 * v0; g11 += v1 * v1; g22 += v2 * v2;
                    g01 += v0 * v1; g02 += v0 * v2; g12 += v1 * v2;
                }
        asm volatile("s_waitcnt vmcnt(0)" ::: "memory");
        __syncthreads();
        float gv[6] = {g00, g11, g22, g01, g02, g12};
        float* redf = (float*)lds8;
#pragma unroll
        for (int k = 0; k < 6; ++k) {
            float v = gv[k];
#pragma unroll
            for (int s = 32; s; s >>= 1) v += __shfl_down(v, s, 64);
            if (l == 0) redf[w * 6 + k] = v;
        }
        __syncthreads();
        if (tid < 6) {
            float s = 0;
#pragma unroll
            for (int k = 0; k < 8; ++k) s += redf[k * 6 + tid];
            g_part6[tid * 256 + bid] = s;
        }
    }
}

// ---------------- per-row exp-sums (exp-chain) ----------------
__global__ __launch_bounds__(256) void k_rowstat() {
    __shared__ float red[6][4];
    int i = blockIdx.x;
    float rd = fminf(g_rminp[i], g_rminn[i]);
    float rnn = g_rminn[i];
    const float4* rp4 = (const float4*)(g_Sp + (size_t)i * N_);
    const float4* rn4 = (const float4*)(g_Sn + (size_t)i * N_);
    float v[6] = {0, 0, 0, 0, 0, 0};
    for (int c = threadIdx.x; c < 1024; c += 256) {
        float4 a = rp4[c], b = rn4[c];
#pragma unroll
        for (int e = 0; e < 4; ++e) {
            float dp = (&a.x)[e], dn = (&b.x)[e];
            {
                EXPCHAIN((rd - dp) * 5.f, e5, e20, e50)
                v[0] += e50; v[1] += e20; v[2] += e5;
            }
            {
                EXPCHAIN((rd - dn) * 5.f, e5, e20, e50)
                v[0] += e50; v[1] += e20; v[2] += e5;
            }
            {
                EXPCHAIN((rnn - dn) * 5.f, e5, e20, e50)
                v[3] += e50; v[4] += e20; v[5] += e5;
            }
        }
    }
    int l = threadIdx.x & 63, w = threadIdx.x >> 6;
#pragma unroll
    for (int k = 0; k < 6; ++k)
#pragma unroll
        for (int s = 32; s; s >>= 1) v[k] += __shfl_down(v[k], s, 64);
    if (l == 0)
#pragma unroll
        for (int k = 0; k < 6; ++k) red[k][w] = v[k];
    __syncthreads();
    int t = threadIdx.x;
    if (t < 6) {
        float s = red[t][0] + red[t][1] + red[t][2] + red[t][3];
        if (t < 3) g_R[t * N_ + i] = rsqrtf(s);
        else g_Cn[(t - 3) * N_ + i] = rsqrtf(s);
    }
}

// ---------------- column exp-sums of d_pos (exp-chain) ----------------
__global__ __launch_bounds__(256) void k_colexp() {
    int j = blockIdx.x * 256 + threadIdx.x;
    int ch = blockIdx.y;
    int i0 = ch * 512;
    float cm = g_cminp[j];
    float a0 = 0, a1 = 0, a2 = 0;
    for (int i = i0; i < i0 + 512; ++i) {
        EXPCHAIN((cm - g_Sp[(size_t)i * N_ + j]) * 5.f, e5, e20, e50)
        a0 += e50; a1 += e20; a2 += e5;
    }
    g_Cpart[(size_t)ch * (3 * N_) + 0 * N_ + j] = a0;
    g_Cpart[(size_t)ch * (3 * N_) + 1 * N_ + j] = a1;
    g_Cpart[(size_t)ch * (3 * N_) + 2 * N_ + j] = a2;
}
__global__ __launch_bounds__(256) void k_colreduce() {
    int idx = blockIdx.x * 256 + threadIdx.x;
    float s = 0;
#pragma unroll
    for (int ch = 0; ch < 8; ++ch) s += g_Cpart[(size_t)ch * (3 * N_) + idx];
    g_Cp[idx] = rsqrtf(s);
}

// ---------------- fused rowsumA + W generation (exp-chain, fp8 out) ----------
__global__ __launch_bounds__(256) void k_wfuse() {
    __shared__ float sp[4096];
    __shared__ float sn[4096];
    __shared__ float red[6][4];
    __shared__ float bc[6];
    int i = blockIdx.x;
    float rd = fminf(g_rminp[i], g_rminn[i]);
    const float4* rp4 = (const float4*)(g_Sp + (size_t)i * N_);
    const float4* rn4 = (const float4*)(g_Sn + (size_t)i * N_);
    for (int c = threadIdx.x; c < 1024; c += 256) {
        ((float4*)sp)[c] = rp4[c];
        ((float4*)sn)[c] = rn4[c];
    }
    __syncthreads();
    const float iR0 = g_R[i], iR1 = g_R[N_ + i], iR2 = g_R[2 * N_ + i];
    float v[6] = {0, 0, 0, 0, 0, 0};
    for (int j = threadIdx.x; j < 4096; j += 256) {
        {
            EXPCHAIN((0.5f * (rd + g_cminp[j]) - sp[j]) * 5.f, e5, e20, e50)
            v[0] += e50 * g_Cp[j];
            v[1] += e20 * g_Cp[N_ + j];
            v[2] += e5 * g_Cp[2 * N_ + j];
        }
        {
            EXPCHAIN((0.5f * (rd + g_rminn[j]) - sn[j]) * 5.f, e5, e20, e50)
            v[3] += e50 * g_Cn[j];
            v[4] += e20 * g_Cn[N_ + j];
            v[5] += e5 * g_Cn[2 * N_ + j];
        }
    }
    int l = threadIdx.x & 63, w = threadIdx.x >> 6;
#pragma unroll
    for (int k = 0; k < 6; ++k)
#pragma unroll
        for (int s = 32; s; s >>= 1) v[k] += __shfl_down(v[k], s, 64);
    if (l == 0)
#pragma unroll
        for (int k = 0; k < 6; ++k) red[k][w] = v[k];
    __syncthreads();
    if (threadIdx.x < 6) {
        int t = threadIdx.x;
        float s = red[t][0] + red[t][1] + red[t][2] + red[t][3];
        float iR = (t % 3 == 0) ? iR0 : ((t % 3 == 1) ? iR1 : iR2);
        bc[t] = s * iR;
    }
    __syncthreads();
    const float sp0 = bc[0], sp1 = bc[1], sp2 = bc[2];
    const float sn0 = bc[3], sn1 = bc[4], sn2 = bc[5];
    for (int gq = threadIdx.x; gq < 512; gq += 256) {
        int j0 = gq * 8;
        float fp[3][8], fn[3][8];
#pragma unroll
        for (int e = 0; e < 8; ++e) {
            int j = j0 + e;
            {
                EXPCHAIN((0.5f * (rd + g_cminp[j]) - sp[j]) * 5.f, e5, e20, e50)
                fp[0][e] = e50 * iR0 * g_Cp[j] * sn0;
                fp[1][e] = e20 * iR1 * g_Cp[N_ + j] * sn1;
                fp[2][e] = e5 * iR2 * g_Cp[2 * N_ + j] * sn2;
            }
            {
                EXPCHAIN((0.5f * (rd + g_rminn[j]) - sn[j]) * 5.f, e5, e20, e50)
                fn[0][e] = -(e50 * iR0 * g_Cn[j] * sp0);
                fn[1][e] = -(e20 * iR1 * g_Cn[N_ + j] * sp1);
                fn[2][e] = -(e5 * iR2 * g_Cn[2 * N_ + j] * sp2);
            }
        }
#pragma unroll
        for (int t = 0; t < 3; ++t) {
            u16 op[4], on[4];
#pragma unroll
            for (int e2 = 0; e2 < 4; ++e2) {
                op[e2] = cvt2fp8(fp[t][2 * e2], fp[t][2 * e2 + 1]);
                on[e2] = cvt2fp8(fn[t][2 * e2], fn[t][2 * e2 + 1]);
            }
            *(uint2*)&g_Wall[((size_t)t * N_ + i) * (2 * N_) + j0] = *(const uint2*)op;
            *(uint2*)&g_Wall[((size_t)t * N_ + i) * (2 * N_) + 4096 + j0] = *(const uint2*)on;
        }
    }
}

// ---------------- finalize: m from Gram matrix ----------------
__global__ __launch_bounds__(256) void k_finalize(float* out) {
    float g[6];
#pragma unroll
    for (int k = 0; k < 6; ++k) {
        g[k] = blockSum256(g_part6[k * 256 + threadIdx.x]);
    }
    if (threadIdx.x == 0) {
        const float nd = (float)N_ * (float)D_;
        float s0 = rsqrtf(g[0] / nd + 1e-8f);
        float s1 = rsqrtf(g[1] / nd + 1e-8f);
        float s2 = rsqrtf(g[2] / nd + 1e-8f);
        float m = (g[0] * s0 * s0 + g[1] * s1 * s1 + g[2] * s2 * s2 +
                   2.f * (g[3] * s0 * s1 + g[4] * s0 * s2 + g[5] * s1 * s2)) / nd;
        out[0] = m / (m + 1e-8f);
    }
}

// ---------------- host orchestration ----------------
extern "C" void kernel_launch(void* const* d_in, const int* in_sizes, int n_in,
                              void* d_out, int out_size, void* d_ws, size_t ws_size,
                              hipStream_t stream) {
    const float* xg = (const float*)d_in[0];
    const float* xp = (const float*)d_in[1];
    float* out = (float*)d_out;

    k_convtrans<<<dim3(N_ / 32, 2), dim3(32, 8), 0, stream>>>(xg, xp);

    k_gemmS<<<392, 512, 0, stream>>>();      // MX fp8: dist + mins

    k_rowstat<<<N_, 256, 0, stream>>>();
    k_colexp<<<dim3(N_ / 256, 8), 256, 0, stream>>>();
    k_colreduce<<<3 * N_ / 256, 256, 0, stream>>>();
    k_wfuse<<<N_, 256, 0, stream>>>();

    k_gemmV<0><<<512, 512, 0, stream>>>();   // V_0, V_1 -> g_Vall
    k_gemmV<1><<<256, 512, 0, stream>>>();   // V_2 in-reg + Gram partials

    k_finalize<<<1, 256, 0, stream>>>(out);
}

// Round 20
// 662.041 us; speedup vs baseline: 1.2502x; 1.0648x over previous
//
#include <hip/hip_runtime.h>
#include <hip/hip_bf16.h>

typedef unsigned short u16;
typedef unsigned char u8;
typedef float f32x4 __attribute__((ext_vector_type(4)));
typedef int i32x4v __attribute__((ext_vector_type(4)));
typedef int i32x8v __attribute__((ext_vector_type(8)));

#define N_ 4096
#define D_ 3072

// ---------------- static device workspace ----------------
__device__ __align__(256) u8   g_Feat8[(size_t)2 * N_ * D_];     // fp8 [G rows ; P rows]
__device__ __align__(256) u8   g_BT[(size_t)(D_ + 64) * 2 * N_]; // fp8 [3072(+64)][8192] = [PbT | GbT]
__device__ __align__(256) u8   g_Wall[(size_t)3 * N_ * 2 * N_];  // fp8 [tau][4096][8192] = [Wp | -Wn]
__device__ __align__(256) u16  g_Sp[(size_t)N_ * N_];            // dist_pos (bf16)
__device__ __align__(256) u16  g_Sn[(size_t)N_ * N_];            // dist_neg (bf16, +diag mask)
__device__ __align__(256) u16  g_Vall[(size_t)2 * N_ * D_];      // V_0, V_1 (bf16; V_2 never stored)
__device__ float g_ng[N_], g_np[N_];
__device__ float g_rminp[N_], g_rminn[N_], g_cminp[N_];          // via atomicMin in S-GEMM
__device__ float g_R [3 * N_];    // rsqrt(row exp-sums)
__device__ float g_Cp[3 * N_];    // rsqrt(col exp-sums, pos)
__device__ float g_Cn[3 * N_];    // rsqrt(col exp-sums, neg = row sums by symmetry)
__device__ float g_Cpart[8 * 3 * N_];
__device__ float g_part6[6 * 256];   // Gram partials G00,G11,G22,G01,G02,G12

// ---------------- helpers ----------------
__device__ __forceinline__ u16 cvt2fp8(float a, float b) {
    return (u16)(__builtin_amdgcn_cvt_pk_fp8_f32(a, b, 0, false) & 0xffff);
}
__device__ __forceinline__ u8 cvt1fp8(float a) {
    return (u8)(__builtin_amdgcn_cvt_pk_fp8_f32(a, a, 0, false) & 0xff);
}
__device__ __forceinline__ u16 f2bf(float f) {
    unsigned u = __float_as_uint(f);
    u += 0x7fffu + ((u >> 16) & 1u);
    return (u16)(u >> 16);
}
__device__ __forceinline__ float b2f(u16 h) {
    return __uint_as_float((unsigned)h << 16);
}

// exp chain: from e1 = exp(5x) derive e20 = e1^4, e50 = e1^10 (4 muls)
#define EXPCHAIN(x5, E5, E20, E50) \
    float E5 = __expf(x5); float E5##_2 = E5 * E5; float E20 = E5##_2 * E5##_2; \
    float E50 = E20 * E20 * E5##_2;

__device__ __forceinline__ float blockSum256(float v) {
    __shared__ float red[4];
#pragma unroll
    for (int s = 32; s; s >>= 1) v += __shfl_down(v, s, 64);
    int l = threadIdx.x & 63, w = threadIdx.x >> 6;
    if (l == 0) red[w] = v;
    __syncthreads();
    float r = red[0] + red[1] + red[2] + red[3];
    __syncthreads();
    return r;
}

__device__ __forceinline__ void gload16(const void* g, void* lds) {
    __builtin_amdgcn_global_load_lds(
        (const __attribute__((address_space(1))) void*)g,
        (__attribute__((address_space(3))) void*)lds, 16, 0, 0);
}

__device__ __forceinline__ void atomicMinF(float* p, float v) {
    atomicMin((unsigned int*)p, __float_as_uint(v));   // exact for v >= 0
}

// ---- fused convert(fp8) + row norms + transpose + min-array init ----
__global__ __launch_bounds__(256) void k_convtrans(const float* __restrict__ Xg,
                                                   const float* __restrict__ Xp) {
    const int sel = blockIdx.y;
    const int tid256 = threadIdx.y * 32 + threadIdx.x;
    if (sel == 0 && tid256 < 96) {
        int idx = blockIdx.x * 96 + tid256;   // 0..12287
        if (idx < N_) g_rminp[idx] = 1e30f;
        else if (idx < 2 * N_) g_rminn[idx - N_] = 1e30f;
        else g_cminp[idx - 2 * N_] = 1e30f;
    }
    const float* X = sel ? Xp : Xg;
    u8* Xb = g_Feat8 + (size_t)sel * N_ * D_;
    float* nr = sel ? g_np : g_ng;
    const int colofs = sel ? 0 : 4096;
    __shared__ u8 t8[128][33];
    const int r0 = blockIdx.x * 32;
    const int tx = threadIdx.x, ty = threadIdx.y;
    float a[4] = {0, 0, 0, 0};
    for (int c0 = 0; c0 < D_; c0 += 128) {
#pragma unroll
        for (int kk = 0; kk < 4; ++kk) {
            const int r = r0 + ty + kk * 8;
#pragma unroll
            for (int cc = 0; cc < 4; ++cc) {
                const int c = c0 + cc * 32 + tx;
                float v = X[(size_t)r * D_ + c];
                a[kk] += v * v;
                u8 b8 = cvt1fp8(v);
                Xb[(size_t)r * D_ + c] = b8;
                t8[cc * 32 + tx][ty + kk * 8] = b8;
            }
        }
        __syncthreads();
#pragma unroll
        for (int qq = 0; qq < 16; ++qq) {
            const int q = qq * 8 + ty;
            g_BT[(size_t)(c0 + q) * (2 * N_) + colofs + r0 + tx] = t8[q][tx];
        }
        __syncthreads();
    }
#pragma unroll
    for (int j = 0; j < 4; ++j) {
        float v = a[j];
        v += __shfl_xor(v, 1, 64);
        v += __shfl_xor(v, 2, 64);
        v += __shfl_xor(v, 4, 64);
        v += __shfl_xor(v, 8, 64);
        v += __shfl_xor(v, 16, 64);
        if (tx == 0) nr[r0 + ty + 8 * j] = v;
    }
}

// ---------------- S-GEMM (MX fp8, K=128, unit scales) — R16-proven ----------
__global__ __launch_bounds__(512, 1) void k_gemmS() {
    constexpr int NF = 4;
    constexpr int Kb = D_;
    constexpr int nT = Kb >> 7;       // 24 super-tiles

    __shared__ u8 lds8[131072];       // A: 2x32KB @0 ; B: 2x32KB @65536

    const int nwg = gridDim.x;
    const int cpx = nwg >> 3;
    const int bid = blockIdx.x;
    const int swz = (bid & 7) * cpx + (bid >> 3);

    int i0, j0, jfeat;
    bool isSn = false, isDiag = false;
    if (swz < 256) {
        const int by = swz >> 4, bx = swz & 15;
        i0 = by * 256; j0 = bx * 256; jfeat = 4096 + j0;
    } else {
        int t = swz - 256, by = 0;
        while (t >= 16 - by) { t -= 16 - by; ++by; }
        const int bx = by + t;
        i0 = by * 256; j0 = bx * 256; jfeat = j0;
        isSn = true; isDiag = (bx == by);
    }

    const int tid = threadIdx.x;
    const int l = tid & 63, w = tid >> 6;
    const int wr = w >> 2, wc = w & 3;
    const int fr = l & 15, kg = l >> 4;

    const int lrow = w * 8 + (l >> 3);
    const int schunk = ((l & 7) ^ (l >> 3)) * 16;
    const u8* aB = g_Feat8 + (size_t)(i0 + lrow) * Kb + schunk;
    const u8* bB = g_Feat8 + (size_t)(jfeat + lrow) * Kb + schunk;

    f32x4 acc[8][NF] = {};

#define STAGE_S(T) {                                                         \
        const int sA_ = ((T) & 1) * 32768;                                   \
        const int sB_ = 65536 + ((T) & 1) * 32768;                           \
        _Pragma("unroll") for (int a = 0; a < 4; ++a)                        \
            gload16(aB + (size_t)(a * 64) * Kb + (T) * 128,                  \
                    lds8 + sA_ + (w * 8 + a * 64) * 128);                    \
        _Pragma("unroll") for (int b = 0; b < 4; ++b)                        \
            gload16(bB + (size_t)(b * 64) * Kb + (T) * 128,                  \
                    lds8 + sB_ + (w * 8 + b * 64) * 128);                    \
    }

#define RDFRAG_S(dst, slotbase, ROW) {                                       \
        const char* base_ = (const char*)lds8 + (slotbase) + (ROW) * 128;    \
        i32x4v lo_ = *(const i32x4v*)(base_ + (((kg * 2) ^ ((ROW) & 7)) * 16));     \
        i32x4v hi_ = *(const i32x4v*)(base_ + (((kg * 2 + 1) ^ ((ROW) & 7)) * 16)); \
        dst = __builtin_shufflevector(lo_, hi_, 0, 1, 2, 3, 4, 5, 6, 7);     \
    }

    STAGE_S(0);

    for (int T = 0; T < nT; ++T) {
        const int sA = (T & 1) * 32768;
        const int sB = 65536 + (T & 1) * 32768;
        asm volatile("s_waitcnt vmcnt(0)" ::: "memory");
        asm volatile("s_barrier" ::: "memory");

        i32x8v av[4], bv[NF];
#pragma unroll
        for (int m = 0; m < 4; ++m) {
            int row = wr * 128 + m * 16 + fr;
            RDFRAG_S(av[m], sA, row);
        }
#pragma unroll
        for (int n = 0; n < NF; ++n) {
            int row = wc * (NF * 16) + n * 16 + fr;
            RDFRAG_S(bv[n], sB, row);
        }
        { int Tn = T + 1; if (Tn > nT - 1) Tn = nT - 1; STAGE_S(Tn); }

        asm volatile("s_waitcnt lgkmcnt(0)" ::: "memory");
        __builtin_amdgcn_sched_barrier(0);
        __builtin_amdgcn_s_setprio(1);
#pragma unroll
        for (int m = 0; m < 4; ++m)
#pragma unroll
            for (int n = 0; n < NF; ++n)
                acc[m][n] = __builtin_amdgcn_mfma_scale_f32_16x16x128_f8f6f4(
                    av[m], bv[n], acc[m][n], 0, 0, 0, 0x7F7F7F7F, 0, 0x7F7F7F7F);
        __builtin_amdgcn_s_setprio(0);

#pragma unroll
        for (int m = 0; m < 4; ++m) {
            int row = wr * 128 + (4 + m) * 16 + fr;
            RDFRAG_S(av[m], sA, row);
        }
        asm volatile("s_waitcnt lgkmcnt(0)" ::: "memory");
        __builtin_amdgcn_sched_barrier(0);
        __builtin_amdgcn_s_setprio(1);
#pragma unroll
        for (int m = 0; m < 4; ++m)
#pragma unroll
            for (int n = 0; n < NF; ++n)
                acc[4 + m][n] = __builtin_amdgcn_mfma_scale_f32_16x16x128_f8f6f4(
                    av[m], bv[n], acc[4 + m][n], 0, 0, 0, 0x7F7F7F7F, 0, 0x7F7F7F7F);
        __builtin_amdgcn_s_setprio(0);
    }
#undef STAGE_S
#undef RDFRAG_S

    const int fq = l >> 4;
    u16* Sd = isSn ? g_Sn : g_Sp;
    const float* nb = isSn ? g_ng : g_np;
    float cmin[NF];
#pragma unroll
    for (int n = 0; n < NF; ++n) cmin[n] = 1e30f;

#pragma unroll
    for (int m = 0; m < 8; ++m) {
        const int row0 = i0 + wr * 128 + m * 16 + fq * 4;
        float rmin[4] = {1e30f, 1e30f, 1e30f, 1e30f};
#pragma unroll
        for (int n = 0; n < NF; ++n) {
            const int col = j0 + wc * 64 + n * 16 + fr;
            const float nbc = nb[col];
            u16 dm4[4];
#pragma unroll
            for (int r = 0; r < 4; ++r) {
                const int row = row0 + r;
                float d2 = g_ng[row] + nbc - 2.f * acc[m][n][r];
                float d = sqrtf(fmaxf(d2, 0.f));
                if (isSn && col == row) d += 1000000.0f;
                u16 db = f2bf(d);
                float dr = b2f(db);        // rounded value used for mins (consistency)
                Sd[(size_t)row * 4096 + col] = db;
                dm4[r] = db;
                rmin[r] = fminf(rmin[r], dr);
                cmin[n] = fminf(cmin[n], dr);
            }
            if (isSn && !isDiag)   // mirror tile, 8B store (4 bf16)
                *(uint2*)&g_Sn[(size_t)col * 4096 + row0] = *(const uint2*)dm4;
        }
#pragma unroll
        for (int r = 0; r < 4; ++r) {
            float v = rmin[r];
            v = fminf(v, __shfl_xor(v, 1, 64));
            v = fminf(v, __shfl_xor(v, 2, 64));
            v = fminf(v, __shfl_xor(v, 4, 64));
            v = fminf(v, __shfl_xor(v, 8, 64));
            if (fr == 0) atomicMinF(isSn ? &g_rminn[row0 + r] : &g_rminp[row0 + r], v);
        }
    }
#pragma unroll
    for (int n = 0; n < NF; ++n) {
        float v = cmin[n];
        v = fminf(v, __shfl_xor(v, 16, 64));
        v = fminf(v, __shfl_xor(v, 32, 64));
        if (kg == 0) {
            const int col = j0 + wc * 64 + n * 16 + fr;
            atomicMinF(isSn ? &g_rminn[col] : &g_cminp[col], v);
        }
    }
}

// ---------------- V-GEMM (MX fp8 K=128, R13/R17-proven core, BM=256) --------
template <int GRAM>
__global__ __launch_bounds__(512, 1) void k_gemmV() {
    constexpr int NF = 3;
    constexpr int Kb = 2 * N_;        // 8192 bytes
    constexpr int nT = Kb >> 7;       // 64 super-tiles

    __shared__ u8 lds8[114688];       // A: 2x32KB @0 ; B: 2x24KB @65536

    const int nwg = gridDim.x;
    const int cpx = nwg >> 3;
    const int bid = blockIdx.x;
    const int swz = (bid & 7) * cpx + (bid >> 3);
    const int tsel = GRAM ? 2 : (swz >> 8);
    const int tile = GRAM ? swz : (swz & 255);
    const int by = tile >> 4, bx = tile & 15;
    const int i0 = by * 256, j0 = bx * (NF * 64);
    const u8* Am = g_Wall + (size_t)tsel * N_ * 2 * N_;
    const u8* Bm = g_BT;

    const int tid = threadIdx.x;
    const int l = tid & 63, w = tid >> 6;
    const int wr = w >> 2, wc = w & 3;
    const int fr = l & 15, kg = l >> 4;

    const int lrow = w * 8 + (l >> 3);
    const int schunk = ((l & 7) ^ (l >> 3)) * 16;
    const u8* aB = Am + (size_t)(i0 + lrow) * Kb + schunk;
    const u8* bB = Bm + (size_t)(j0 + lrow) * Kb + schunk;

    f32x4 acc[8][NF] = {};

#define STAGE_T(T) {                                                         \
        const int sA_ = ((T) & 1) * 32768;                                   \
        const int sB_ = 65536 + ((T) & 1) * 24576;                           \
        _Pragma("unroll") for (int a = 0; a < 4; ++a)                        \
            gload16(aB + (size_t)(a * 64) * Kb + (T) * 128,                  \
                    lds8 + sA_ + (w * 8 + a * 64) * 128);                    \
        _Pragma("unroll") for (int b = 0; b < 3; ++b)                        \
            gload16(bB + (size_t)(b * 64) * Kb + (T) * 128,                  \
                    lds8 + sB_ + (w * 8 + b * 64) * 128);                    \
    }

#define RDFRAG(dst, slotbase, ROW) {                                         \
        const char* base_ = (const char*)lds8 + (slotbase) + (ROW) * 128;    \
        i32x4v lo_ = *(const i32x4v*)(base_ + (((kg * 2) ^ ((ROW) & 7)) * 16));     \
        i32x4v hi_ = *(const i32x4v*)(base_ + (((kg * 2 + 1) ^ ((ROW) & 7)) * 16)); \
        dst = __builtin_shufflevector(lo_, hi_, 0, 1, 2, 3, 4, 5, 6, 7);     \
    }

    STAGE_T(0);

    for (int T = 0; T < nT; ++T) {
        const int sA = (T & 1) * 32768;
        const int sB = 65536 + (T & 1) * 24576;
        asm volatile("s_waitcnt vmcnt(0)" ::: "memory");
        asm volatile("s_barrier" ::: "memory");

        i32x8v av[4], bv[NF];
#pragma unroll
        for (int m = 0; m < 4; ++m) {
            int row = wr * 128 + m * 16 + fr;
            RDFRAG(av[m], sA, row);
        }
#pragma unroll
        for (int n = 0; n < NF; ++n) {
            int row = wc * (NF * 16) + n * 16 + fr;
            RDFRAG(bv[n], sB, row);
        }
        { int Tn = T + 1; if (Tn > nT - 1) Tn = nT - 1; STAGE_T(Tn); }

        asm volatile("s_waitcnt lgkmcnt(0)" ::: "memory");
        __builtin_amdgcn_sched_barrier(0);
        __builtin_amdgcn_s_setprio(1);
#pragma unroll
        for (int m = 0; m < 4; ++m)
#pragma unroll
            for (int n = 0; n < NF; ++n)
                acc[m][n] = __builtin_amdgcn_mfma_scale_f32_16x16x128_f8f6f4(
                    av[m], bv[n], acc[m][n], 0, 0, 0, 0x7F7F7F7F, 0, 0x7F7F7F7F);
        __builtin_amdgcn_s_setprio(0);

#pragma unroll
        for (int m = 0; m < 4; ++m) {
            int row = wr * 128 + (4 + m) * 16 + fr;
            RDFRAG(av[m], sA, row);
        }
        asm volatile("s_waitcnt lgkmcnt(0)" ::: "memory");
        __builtin_amdgcn_sched_barrier(0);
        __builtin_amdgcn_s_setprio(1);
#pragma unroll
        for (int m = 0; m < 4; ++m)
#pragma unroll
            for (int n = 0; n < NF; ++n)
                acc[4 + m][n] = __builtin_amdgcn_mfma_scale_f32_16x16x128_f8f6f4(
                    av[m], bv[n], acc[4 + m][n], 0, 0, 0, 0x7F7F7F7F, 0, 0x7F7F7F7F);
        __builtin_amdgcn_s_setprio(0);
    }
#undef STAGE_T
#undef RDFRAG

    const int fq = l >> 4;
    if (GRAM == 0) {
        u16* Vout = g_Vall + (size_t)tsel * N_ * D_;
#pragma unroll
        for (int m = 0; m < 8; ++m)
#pragma unroll
            for (int n = 0; n < NF; ++n)
#pragma unroll
                for (int r = 0; r < 4; ++r) {
                    int row = i0 + wr * 128 + m * 16 + fq * 4 + r;
                    int col = j0 + wc * (NF * 16) + n * 16 + fr;
                    Vout[(size_t)row * D_ + col] = f2bf(acc[m][n][r]);
                }
    } else {
        const u16* V0 = g_Vall;
        const u16* V1 = g_Vall + (size_t)N_ * D_;
        float g00 = 0, g11 = 0, g22 = 0, g01 = 0, g02 = 0, g12 = 0;
#pragma unroll
        for (int m = 0; m < 8; ++m)
#pragma unroll
            for (int n = 0; n < NF; ++n)
#pragma unroll
                for (int r = 0; r < 4; ++r) {
                    int row = i0 + wr * 128 + m * 16 + fq * 4 + r;
                    int col = j0 + wc * (NF * 16) + n * 16 + fr;
                    size_t idx = (size_t)row * D_ + col;
                    float v2 = acc[m][n][r];
                    float v0 = b2f(V0[idx]), v1 = b2f(V1[idx]);
                    g00 += v0 * v0; g11 += v1 * v1; g22 += v2 * v2;
                    g01 += v0 * v1; g02 += v0 * v2; g12 += v1 * v2;
                }
        asm volatile("s_waitcnt vmcnt(0)" ::: "memory");
        __syncthreads();
        float gv[6] = {g00, g11, g22, g01, g02, g12};
        float* redf = (float*)lds8;
#pragma unroll
        for (int k = 0; k < 6; ++k) {
            float v = gv[k];
#pragma unroll
            for (int s = 32; s; s >>= 1) v += __shfl_down(v, s, 64);
            if (l == 0) redf[w * 6 + k] = v;
        }
        __syncthreads();
        if (tid < 6) {
            float s = 0;
#pragma unroll
            for (int k = 0; k < 8; ++k) s += redf[k * 6 + tid];
            g_part6[tid * 256 + bid] = s;
        }
    }
}

// ---------------- per-row exp-sums (bf16 reads, exp-chain) ----------------
__global__ __launch_bounds__(256) void k_rowstat() {
    __shared__ float red[6][4];
    int i = blockIdx.x;
    float rd = fminf(g_rminp[i], g_rminn[i]);
    float rnn = g_rminn[i];
    const uint4* rp4 = (const uint4*)(g_Sp + (size_t)i * N_);
    const uint4* rn4 = (const uint4*)(g_Sn + (size_t)i * N_);
    float v[6] = {0, 0, 0, 0, 0, 0};
    for (int c = threadIdx.x; c < 512; c += 256) {
        uint4 a = rp4[c], b = rn4[c];
#pragma unroll
        for (int e = 0; e < 8; ++e) {
            float dp = b2f(((const u16*)&a)[e]);
            float dn = b2f(((const u16*)&b)[e]);
            {
                EXPCHAIN((rd - dp) * 5.f, e5, e20, e50)
                v[0] += e50; v[1] += e20; v[2] += e5;
            }
            {
                EXPCHAIN((rd - dn) * 5.f, e5, e20, e50)
                v[0] += e50; v[1] += e20; v[2] += e5;
            }
            {
                EXPCHAIN((rnn - dn) * 5.f, e5, e20, e50)
                v[3] += e50; v[4] += e20; v[5] += e5;
            }
        }
    }
    int l = threadIdx.x & 63, w = threadIdx.x >> 6;
#pragma unroll
    for (int k = 0; k < 6; ++k)
#pragma unroll
        for (int s = 32; s; s >>= 1) v[k] += __shfl_down(v[k], s, 64);
    if (l == 0)
#pragma unroll
        for (int k = 0; k < 6; ++k) red[k][w] = v[k];
    __syncthreads();
    int t = threadIdx.x;
    if (t < 6) {
        float s = red[t][0] + red[t][1] + red[t][2] + red[t][3];
        if (t < 3) g_R[t * N_ + i] = rsqrtf(s);
        else g_Cn[(t - 3) * N_ + i] = rsqrtf(s);
    }
}

// ---------------- column exp-sums of d_pos (bf16 reads, exp-chain) -----------
__global__ __launch_bounds__(256) void k_colexp() {
    int j = blockIdx.x * 256 + threadIdx.x;
    int ch = blockIdx.y;
    int i0 = ch * 512;
    float cm = g_cminp[j];
    float a0 = 0, a1 = 0, a2 = 0;
    for (int i = i0; i < i0 + 512; ++i) {
        float dv = b2f(g_Sp[(size_t)i * N_ + j]);
        EXPCHAIN((cm - dv) * 5.f, e5, e20, e50)
        a0 += e50; a1 += e20; a2 += e5;
    }
    g_Cpart[(size_t)ch * (3 * N_) + 0 * N_ + j] = a0;
    g_Cpart[(size_t)ch * (3 * N_) + 1 * N_ + j] = a1;
    g_Cpart[(size_t)ch * (3 * N_) + 2 * N_ + j] = a2;
}
__global__ __launch_bounds__(256) void k_colreduce() {
    int idx = blockIdx.x * 256 + threadIdx.x;
    float s = 0;
#pragma unroll
    for (int ch = 0; ch < 8; ++ch) s += g_Cpart[(size_t)ch * (3 * N_) + idx];
    g_Cp[idx] = rsqrtf(s);
}

// ---------------- fused rowsumA + W generation (bf16 reads, fp8 out) ---------
__global__ __launch_bounds__(256) void k_wfuse() {
    __shared__ float sp[4096];
    __shared__ float sn[4096];
    __shared__ float red[6][4];
    __shared__ float bc[6];
    int i = blockIdx.x;
    float rd = fminf(g_rminp[i], g_rminn[i]);
    const uint4* rp4 = (const uint4*)(g_Sp + (size_t)i * N_);
    const uint4* rn4 = (const uint4*)(g_Sn + (size_t)i * N_);
    for (int c = threadIdx.x; c < 512; c += 256) {
        uint4 a = rp4[c], b = rn4[c];
        float4 f0, f1, g0, g1;
#pragma unroll
        for (int e = 0; e < 4; ++e) {
            (&f0.x)[e] = b2f(((const u16*)&a)[e]);
            (&f1.x)[e] = b2f(((const u16*)&a)[4 + e]);
            (&g0.x)[e] = b2f(((const u16*)&b)[e]);
            (&g1.x)[e] = b2f(((const u16*)&b)[4 + e]);
        }
        ((float4*)sp)[c * 2] = f0; ((float4*)sp)[c * 2 + 1] = f1;
        ((float4*)sn)[c * 2] = g0; ((float4*)sn)[c * 2 + 1] = g1;
    }
    __syncthreads();
    const float iR0 = g_R[i], iR1 = g_R[N_ + i], iR2 = g_R[2 * N_ + i];
    float v[6] = {0, 0, 0, 0, 0, 0};
    for (int j = threadIdx.x; j < 4096; j += 256) {
        {
            EXPCHAIN((0.5f * (rd + g_cminp[j]) - sp[j]) * 5.f, e5, e20, e50)
            v[0] += e50 * g_Cp[j];
            v[1] += e20 * g_Cp[N_ + j];
            v[2] += e5 * g_Cp[2 * N_ + j];
        }
        {
            EXPCHAIN((0.5f * (rd + g_rminn[j]) - sn[j]) * 5.f, e5, e20, e50)
            v[3] += e50 * g_Cn[j];
            v[4] += e20 * g_Cn[N_ + j];
            v[5] += e5 * g_Cn[2 * N_ + j];
        }
    }
    int l = threadIdx.x & 63, w = threadIdx.x >> 6;
#pragma unroll
    for (int k = 0; k < 6; ++k)
#pragma unroll
        for (int s = 32; s; s >>= 1) v[k] += __shfl_down(v[k], s, 64);
    if (l == 0)
#pragma unroll
        for (int k = 0; k < 6; ++k) red[k][w] = v[k];
    __syncthreads();
    if (threadIdx.x < 6) {
        int t = threadIdx.x;
        float s = red[t][0] + red[t][1] + red[t][2] + red[t][3];
        float iR = (t % 3 == 0) ? iR0 : ((t % 3 == 1) ? iR1 : iR2);
        bc[t] = s * iR;
    }
    __syncthreads();
    const float sp0 = bc[0], sp1 = bc[1], sp2 = bc[2];
    const float sn0 = bc[3], sn1 = bc[4], sn2 = bc[5];
    for (int gq = threadIdx.x; gq < 512; gq += 256) {
        int j0 = gq * 8;
        float fp[3][8], fn[3][8];
#pragma unroll
        for (int e = 0; e < 8; ++e) {
            int j = j0 + e;
            {
                EXPCHAIN((0.5f * (rd + g_cminp[j]) - sp[j]) * 5.f, e5, e20, e50)
                fp[0][e] = e50 * iR0 * g_Cp[j] * sn0;
                fp[1][e] = e20 * iR1 * g_Cp[N_ + j] * sn1;
                fp[2][e] = e5 * iR2 * g_Cp[2 * N_ + j] * sn2;
            }
            {
                EXPCHAIN((0.5f * (rd + g_rminn[j]) - sn[j]) * 5.f, e5, e20, e50)
                fn[0][e] = -(e50 * iR0 * g_Cn[j] * sp0);
                fn[1][e] = -(e20 * iR1 * g_Cn[N_ + j] * sp1);
                fn[2][e] = -(e5 * iR2 * g_Cn[2 * N_ + j] * sp2);
            }
        }
#pragma unroll
        for (int t = 0; t < 3; ++t) {
            u16 op[4], on[4];
#pragma unroll
            for (int e2 = 0; e2 < 4; ++e2) {
                op[e2] = cvt2fp8(fp[t][2 * e2], fp[t][2 * e2 + 1]);
                on[e2] = cvt2fp8(fn[t][2 * e2], fn[t][2 * e2 + 1]);
            }
            *(uint2*)&g_Wall[((size_t)t * N_ + i) * (2 * N_) + j0] = *(const uint2*)op;
            *(uint2*)&g_Wall[((size_t)t * N_ + i) * (2 * N_) + 4096 + j0] = *(const uint2*)on;
        }
    }
}

// ---------------- finalize: m from Gram matrix ----------------
__global__ __launch_bounds__(256) void k_finalize(float* out) {
    float g[6];
#pragma unroll
    for (int k = 0; k < 6; ++k) {
        g[k] = blockSum256(g_part6[k * 256 + threadIdx.x]);
    }
    if (threadIdx.x == 0) {
        const float nd = (float)N_ * (float)D_;
        float s0 = rsqrtf(g[0] / nd + 1e-8f);
        float s1 = rsqrtf(g[1] / nd + 1e-8f);
        float s2 = rsqrtf(g[2] / nd + 1e-8f);
        float m = (g[0] * s0 * s0 + g[1] * s1 * s1 + g[2] * s2 * s2 +
                   2.f * (g[3] * s0 * s1 + g[4] * s0 * s2 + g[5] * s1 * s2)) / nd;
        out[0] = m / (m + 1e-8f);
    }
}

// ---------------- host orchestration ----------------
extern "C" void kernel_launch(void* const* d_in, const int* in_sizes, int n_in,
                              void* d_out, int out_size, void* d_ws, size_t ws_size,
                              hipStream_t stream) {
    const float* xg = (const float*)d_in[0];
    const float* xp = (const float*)d_in[1];
    float* out = (float*)d_out;

    k_convtrans<<<dim3(N_ / 32, 2), dim3(32, 8), 0, stream>>>(xg, xp);

    k_gemmS<<<392, 512, 0, stream>>>();      // MX fp8: dist (bf16 out) + mins

    k_rowstat<<<N_, 256, 0, stream>>>();
    k_colexp<<<dim3(N_ / 256, 8), 256, 0, stream>>>();
    k_colreduce<<<3 * N_ / 256, 256, 0, stream>>>();
    k_wfuse<<<N_, 256, 0, stream>>>();

    k_gemmV<0><<<512, 512, 0, stream>>>();   // V_0, V_1 (bf16) -> g_Vall
    k_gemmV<1><<<256, 512, 0, stream>>>();   // V_2 in-reg + Gram partials

    k_finalize<<<1, 256, 0, stream>>>(out);
}